// Round 5
// baseline (551.188 us; speedup 1.0000x reference)
//
#include <hip/hip_runtime.h>
#include <math.h>

// Problem constants
#define EXPERTS 8
#define DDIM 2048
#define HDIM 2048
#define NTOK 4096
#define NPAIR 8192
#define MAXSLOT 10240   // 8192 + 8*255 rounded up (256-padded per expert)
#define MAXTILE 40      // max sum of ceil(cnt_e/256) = 32 + 8

typedef _Float16 f16;
typedef __attribute__((ext_vector_type(8))) _Float16 f16x8;
typedef __attribute__((ext_vector_type(2))) _Float16 f16x2;
typedef __attribute__((ext_vector_type(4))) float f32x4;

// ---- workspace layout (bytes); peak ~193 MB ----
#define GUPT_OFF 0ull            // f16 [E][4096][2048] = 128MB (phase 1)
#define Y_OFF    0ull            // f16 [MAXSLOT][2048] = 41.9MB (phase 2, aliases gup_t)
#define DWNT_OFF 41943040ull     // f16 [E][2048][2048] = 64MB (phase 2)
#define XF_OFF   134217728ull    // f16 [NTOK][2048] = 16MB
#define ACT_OFF  150994944ull    // f16 [MAXSLOT][2048] = 41.9MB
#define CTRL_OFF 192937984ull
// ctrl (ints): slot_tok[10240]@0, tok_slot[8192]@10240, cnt[8]@18432,
// cursor[8]@18440, tile_e[40]@18448, tile_r0[40]@18488, n_tiles@18528,
// is32@18529, slot_w(float)[10240]@18536
#define CTRL_INTS 28776

#define BARRIER() asm volatile("s_barrier" ::: "memory")
#define VMCNT3()  asm volatile("s_waitcnt vmcnt(3)" ::: "memory")
#define VMCNT2()  asm volatile("s_waitcnt vmcnt(2)" ::: "memory")
#define VMCNT0()  asm volatile("s_waitcnt vmcnt(0)" ::: "memory")

__device__ __forceinline__ void gload_lds16(const void* g, void* l) {
  __builtin_amdgcn_global_load_lds(
      (const __attribute__((address_space(1))) unsigned int*)g,
      (__attribute__((address_space(3))) unsigned int*)l,
      16, 0, 0);
}

// 16B-chunk swizzle within a 32-f16 (64B) row: 2-way bank aliasing only (free)
__device__ __forceinline__ int swz(int r) { return (r + (r >> 2)) & 3; }

// ---------------- routing ----------------
__global__ void k_detect(const int* __restrict__ w, int* flag) {
  int i = blockIdx.x * blockDim.x + threadIdx.x;
  if (i < NPAIR / 2 && w[2 * i + 1] != 0) atomicOr(flag, 1);
}

__device__ __forceinline__ int expert_of(const int* idx, int is32, int p) {
  return is32 ? idx[p] : idx[2 * p];
}

__global__ void k_count(const int* __restrict__ idx, const int* __restrict__ flag,
                        int* cnt) {
  int p = blockIdx.x * blockDim.x + threadIdx.x;
  if (p < NPAIR) atomicAdd(&cnt[expert_of(idx, *flag, p)], 1);
}

__global__ void k_plan(const int* __restrict__ cnt, int* cursor,
                       int* tile_e, int* tile_r0, int* n_tiles) {
  if (blockIdx.x == 0 && threadIdx.x == 0) {
    int off = 0, nt = 0;
    for (int e = 0; e < EXPERTS; ++e) {
      cursor[e] = off;
      int t = (cnt[e] + 255) >> 8;
      for (int i = 0; i < t; ++i) { tile_e[nt] = e; tile_r0[nt] = off + i * 256; ++nt; }
      off += t * 256;
    }
    *n_tiles = nt;
  }
}

__global__ void k_assign(const int* __restrict__ idx, const int* __restrict__ flag,
                         const float* __restrict__ wts, const float* __restrict__ scale,
                         int* cursor, int* slot_tok, int* tok_slot, float* slot_w) {
  int p = blockIdx.x * blockDim.x + threadIdx.x;
  if (p < NPAIR) {
    int e = expert_of(idx, *flag, p);
    int pos = atomicAdd(&cursor[e], 1);
    slot_tok[pos] = p >> 1;
    tok_slot[p] = pos;
    slot_w[pos] = wts[p] * scale[e];
  }
}

__global__ void k_cvt_x(const float* __restrict__ in, f16* __restrict__ out) {
  int i = blockIdx.x * blockDim.x + threadIdx.x;
  float4 v = ((const float4*)in)[i];
  typedef __attribute__((ext_vector_type(4))) _Float16 f16x4;
  f16x4 o = {(f16)v.x, (f16)v.y, (f16)v.z, (f16)v.w};
  ((f16x4*)out)[i] = o;
}

// fp32 [R][C] -> f16 [C][R], per expert (blockIdx.z); f16x2 stores
__global__ void k_transpose(const float* __restrict__ in, f16* __restrict__ out,
                            int R, int C) {
  __shared__ float t[32][33];
  const size_t base = (size_t)blockIdx.z * R * C;
  const float* ip = in + base;
  f16* op = out + base;
  int c0 = blockIdx.x * 32, r0 = blockIdx.y * 32;
  int tx = threadIdx.x, ty = threadIdx.y;
#pragma unroll
  for (int i = 0; i < 32; i += 8)
    t[ty + i][tx] = ip[(size_t)(r0 + ty + i) * C + c0 + tx];
  __syncthreads();
  const int p = tx & 15, h = tx >> 4;
#pragma unroll
  for (int i = 0; i < 2; ++i) {
    const int j = ty + h * 8 + i * 16;
    f16x2 v = {(f16)t[2 * p][j], (f16)t[2 * p + 1][j]};
    *(f16x2*)&op[(size_t)(c0 + j) * R + r0 + 2 * p] = v;
  }
}

// ---------------- 256x64x32 tri-buffered grouped GEMM ----------------
// 8 waves (4M x 2N), wave rows = 64 (wm band), cols: gate/up pairs kept in
// the SAME wave (G1) so the gelu epilogue is wave-local. Tri-buffer LDS,
// 1 barrier + counted vmcnt per K-tile (2-deep prefetch, never drains).
// XCD swizzle is nt-fastest: concurrent blocks on an XCD share ~2 A-tiles
// (L2-resident, 32x reuse); B streams via L3.
// G1: A = gathered x rows; B = gup_t (rows 0-63 gate strip, 64-127 up strip);
//     epilogue: exact gelu(gate)*up -> act.   G0: A = act; B = down_t -> y.
template <int G1>
__global__ __launch_bounds__(512, 4) void k_gemm(
    const f16* __restrict__ Asrc, const f16* __restrict__ Bsrc,
    const int* __restrict__ slot_tok,
    const int* __restrict__ tile_e, const int* __restrict__ tile_r0,
    const int* __restrict__ n_tiles, f16* __restrict__ dst) {
  constexpr int NC = G1 ? 4 : 2;           // acc col-blocks per wave
  constexpr int BUFH = 8192 + (G1 ? 128 : 64) * 32;  // f16 per buffer
  __shared__ __align__(16) f16 smem[3][BUFH];

  // bijective XCD swizzle, nt-fastest within each XCD chunk
  const int q = (MAXTILE * 32) / 8;  // 160
  int oid = (int)(blockIdx.y * MAXTILE + blockIdx.x);
  int nid = (oid & 7) * q + (oid >> 3);
  const int nt = nid & 31, bx = nid >> 5;
  if (bx >= *n_tiles) return;
  const int e = tile_e[bx];
  const int m0 = tile_r0[bx];

  const int tid = threadIdx.x;
  const int lane = tid & 63;
  const int wv = tid >> 6;
  const int wm = wv >> 1;   // 0..3 : 64-row band
  const int wn = wv & 1;    // 0..1 : col-pair group
  const int fr = lane & 15;
  const int fhi = lane >> 4;

  // staging sources (inverse-swizzled chunk; LDS dest linear)
  const int cc = tid & 3;
  const int ar0 = tid >> 2;  // 0..127
  const f16* aS[2];
#pragma unroll
  for (int i = 0; i < 2; ++i) {
    const int rl = i * 128 + ar0;
    size_t arow = G1 ? (size_t)slot_tok[m0 + rl] : (size_t)(m0 + rl);
    aS[i] = Asrc + arow * 2048 + (cc ^ swz(rl)) * 8;
  }
  const f16* bS = nullptr;
  if (G1 || tid < 256) {
    const int rb = tid >> 2;  // G1: 0..127, G0: 0..63
    size_t brow;
    if (G1) brow = (size_t)e * 4096 + (rb < 64 ? (size_t)(nt * 64 + rb)
                                               : (size_t)(2048 + nt * 64 + rb - 64));
    else    brow = (size_t)e * 2048 + nt * 64 + rb;
    bS = Bsrc + brow * 2048 + (cc ^ swz(rb)) * 8;
  }

  auto stage = [&](int s, int kt) {
    const size_t ko = (size_t)kt * 32;
    gload_lds16(aS[0] + ko, &smem[s][tid * 8]);
    gload_lds16(aS[1] + ko, &smem[s][4096 + tid * 8]);
    if (G1 || tid < 256) gload_lds16(bS + ko, &smem[s][8192 + tid * 8]);
  };

  f32x4 acc[4][NC];
#pragma unroll
  for (int i = 0; i < 4; ++i)
#pragma unroll
    for (int j = 0; j < NC; ++j) acc[i][j] = (f32x4){0.f, 0.f, 0.f, 0.f};

  // prologue: 2 stages in flight; complete stage0, keep stage1 flying
  stage(0, 0);
  stage(1, 1);
  if (G1 || wv < 4) { VMCNT3(); } else { VMCNT2(); }
  BARRIER();

  const int NT = 64;  // K / 32
  int s = 0;
  for (int kt = 0; kt < NT; ++kt) {
    int s2 = (s == 0) ? 2 : s - 1;          // (s+2)%3
    if (kt + 2 < NT) stage(s2, kt + 2);

    const f16* As = &smem[s][0];
    const f16* Bs = &smem[s][8192];
    f16x8 af[4];
#pragma unroll
    for (int mi = 0; mi < 4; ++mi) {
      const int r = wm * 64 + mi * 16 + fr;
      af[mi] = *(const f16x8*)&As[r * 32 + ((fhi ^ swz(r)) << 3)];
    }
#pragma unroll
    for (int ci = 0; ci < NC; ++ci) {
      int rb;
      if (G1) rb = (ci < 2 ? 0 : 64) + (wn * 2 + (ci & 1)) * 16 + fr;
      else    rb = (wn * 2 + ci) * 16 + fr;
      const f16x8 b = *(const f16x8*)&Bs[rb * 32 + ((fhi ^ swz(rb)) << 3)];
#pragma unroll
      for (int mi = 0; mi < 4; ++mi)
        acc[mi][ci] = __builtin_amdgcn_mfma_f32_16x16x32_f16(af[mi], b,
                                                             acc[mi][ci], 0, 0, 0);
    }
    if (kt + 1 < NT) {
      if (kt + 2 < NT) { if (G1 || wv < 4) { VMCNT3(); } else { VMCNT2(); } }
      else { VMCNT0(); }
      BARRIER();
    }
    s = (s == 2) ? 0 : s + 1;
  }

  if (G1) {
    // gate col-block g=wn*2+ci (acc ci) pairs with up (acc ci+2) in-wave
#pragma unroll
    for (int mi = 0; mi < 4; ++mi)
#pragma unroll
      for (int ci = 0; ci < 2; ++ci)
#pragma unroll
        for (int rg = 0; rg < 4; ++rg) {
          const int row = m0 + wm * 64 + mi * 16 + fhi * 4 + rg;
          const int col = nt * 64 + (wn * 2 + ci) * 16 + fr;
          const float g = acc[mi][ci][rg];
          const float u = acc[mi][ci + 2][rg];
          const float a = 0.5f * g * (1.0f + erff(g * 0.70710678118654752f)) * u;
          dst[(size_t)row * 2048 + col] = (f16)a;
        }
  } else {
#pragma unroll
    for (int mi = 0; mi < 4; ++mi)
#pragma unroll
      for (int ci = 0; ci < 2; ++ci)
#pragma unroll
        for (int rg = 0; rg < 4; ++rg)
          dst[(size_t)(m0 + wm * 64 + mi * 16 + fhi * 4 + rg) * 2048 +
              nt * 64 + (wn * 2 + ci) * 16 + fr] = (f16)acc[mi][ci][rg];
  }
}

// out[tok] = w(s0)*y[s0] + w(s1)*y[s1]  (fully writes out; no memset needed)
__global__ void k_combine(const f16* __restrict__ y, const float* __restrict__ slot_w,
                          const int* __restrict__ tok_slot, float* __restrict__ out) {
  const int gid = blockIdx.x * blockDim.x + threadIdx.x;
  const int tok = gid >> 8;
  const int c = (gid & 255) * 8;
  const int s0 = tok_slot[2 * tok], s1 = tok_slot[2 * tok + 1];
  const float w0 = slot_w[s0], w1 = slot_w[s1];
  const f16x8 v0 = *(const f16x8*)&y[(size_t)s0 * 2048 + c];
  const f16x8 v1 = *(const f16x8*)&y[(size_t)s1 * 2048 + c];
  float o[8];
#pragma unroll
  for (int j = 0; j < 8; ++j) o[j] = w0 * (float)v0[j] + w1 * (float)v1[j];
  float4* op = (float4*)&out[(size_t)tok * 2048 + c];
  op[0] = (float4){o[0], o[1], o[2], o[3]};
  op[1] = (float4){o[4], o[5], o[6], o[7]};
}

extern "C" void kernel_launch(void* const* d_in, const int* in_sizes, int n_in,
                              void* d_out, int out_size, void* d_ws, size_t ws_size,
                              hipStream_t stream) {
  const float* x = (const float*)d_in[0];
  const float* wts = (const float*)d_in[1];
  const int* idx = (const int*)d_in[2];
  const float* gup = (const float*)d_in[3];
  const float* dwn = (const float*)d_in[4];
  const float* scale = (const float*)d_in[5];
  float* out = (float*)d_out;

  char* ws = (char*)d_ws;
  f16* gup_t = (f16*)(ws + GUPT_OFF);
  f16* y = (f16*)(ws + Y_OFF);          // aliases gup_t (dead after GEMM1)
  f16* down_t = (f16*)(ws + DWNT_OFF);  // aliases gup_t tail (dead after GEMM1)
  f16* xf = (f16*)(ws + XF_OFF);
  f16* act = (f16*)(ws + ACT_OFF);
  int* ctrl = (int*)(ws + CTRL_OFF);
  int* slot_tok = ctrl;
  int* tok_slot = ctrl + 10240;
  int* cnt = ctrl + 18432;
  int* cursor = ctrl + 18440;
  int* tile_e = ctrl + 18448;
  int* tile_r0 = ctrl + 18488;
  int* n_tiles = ctrl + 18528;
  int* is32 = ctrl + 18529;
  float* slot_w = (float*)(ctrl + 18536);

  hipMemsetAsync(ctrl, 0, (size_t)CTRL_INTS * sizeof(int), stream);

  k_detect<<<NPAIR / 2 / 256, 256, 0, stream>>>(idx, is32);
  k_count<<<NPAIR / 256, 256, 0, stream>>>(idx, is32, cnt);
  k_plan<<<1, 1, 0, stream>>>(cnt, cursor, tile_e, tile_r0, n_tiles);
  k_assign<<<NPAIR / 256, 256, 0, stream>>>(idx, is32, wts, scale, cursor,
                                            slot_tok, tok_slot, slot_w);
  k_cvt_x<<<NTOK * DDIM / 4 / 256, 256, 0, stream>>>(x, xf);
  k_transpose<<<dim3(4096 / 32, 2048 / 32, EXPERTS), dim3(32, 8), 0, stream>>>(
      gup, gup_t, 2048, 4096);
  k_gemm<1><<<dim3(MAXTILE, 32), 512, 0, stream>>>(xf, gup_t, slot_tok, tile_e,
                                                   tile_r0, n_tiles, act);
  // gup_t dead now; transpose down into its tail, y into its head
  k_transpose<<<dim3(2048 / 32, 2048 / 32, EXPERTS), dim3(32, 8), 0, stream>>>(
      dwn, down_t, 2048, 2048);
  k_gemm<0><<<dim3(MAXTILE, 32), 512, 0, stream>>>(act, down_t, slot_tok, tile_e,
                                                   tile_r0, n_tiles, y);
  k_combine<<<NTOK, 256, 0, stream>>>(y, slot_w, tok_slot, out);
}

// Round 7
// 517.435 us; speedup vs baseline: 1.0652x; 1.0652x over previous
//
#include <hip/hip_runtime.h>
#include <math.h>

// Problem constants
#define EXPERTS 8
#define DDIM 2048
#define HDIM 2048
#define NTOK 4096
#define NPAIR 8192
#define MAXSLOT 9216    // 8192 + 8*127 rounded up (128-padded per expert)
#define MAXTILE 72      // max sum of ceil(cnt_e/128)

typedef _Float16 f16;
typedef __attribute__((ext_vector_type(8))) _Float16 f16x8;
typedef __attribute__((ext_vector_type(4))) _Float16 f16x4;
typedef __attribute__((ext_vector_type(4))) float f32x4;

// ---- workspace layout (bytes); peak ~92 MB (no weight transposes!) ----
#define XF_OFF   0ull                 // f16 [NTOK][2048]    = 16MB
#define ACT_OFF  16777216ull          // f16 [MAXSLOT][2048] = 37.75MB
#define Y_OFF    54525952ull          // f16 [MAXSLOT][2048] = 37.75MB
#define CTRL_OFF 92274688ull
// ctrl ints: slot_tok[9216]@0, tok_slot[8192]@9216, cnt[8]@17408,
// cursor[8]@17416, tile_e[72]@17424, tile_r0[72]@17496, n_tiles@17568,
// is32@17569, slot_w(float)[9216]@17576
#define CTRL_INTS 26792

#define BARRIER() asm volatile("s_barrier" ::: "memory")
#define VMCNT(n)  asm volatile("s_waitcnt vmcnt(" #n ")" ::: "memory")
#define LGKM0()   asm volatile("s_waitcnt lgkmcnt(0)" ::: "memory")

__device__ __forceinline__ void gload_lds16(const void* g, void* l) {
  __builtin_amdgcn_global_load_lds(
      (const __attribute__((address_space(1))) unsigned int*)g,
      (__attribute__((address_space(3))) unsigned int*)l,
      16, 0, 0);
}

// R4-measured zero-conflict read swizzle for [row][32 f16] tiles
__device__ __forceinline__ int swz(int r) { return (r >> 1) & 3; }

// ---------------- routing ----------------
__global__ void k_detect(const int* __restrict__ w, int* flag) {
  int i = blockIdx.x * blockDim.x + threadIdx.x;
  if (i < NPAIR / 2 && w[2 * i + 1] != 0) atomicOr(flag, 1);
}

__device__ __forceinline__ int expert_of(const int* idx, int is32, int p) {
  return is32 ? idx[p] : idx[2 * p];
}

__global__ void k_count(const int* __restrict__ idx, const int* __restrict__ flag,
                        int* cnt) {
  int p = blockIdx.x * blockDim.x + threadIdx.x;
  if (p < NPAIR) atomicAdd(&cnt[expert_of(idx, *flag, p)], 1);
}

__global__ void k_plan(const int* __restrict__ cnt, int* cursor,
                       int* tile_e, int* tile_r0, int* n_tiles) {
  if (blockIdx.x == 0 && threadIdx.x == 0) {
    int off = 0, nt = 0;
    for (int e = 0; e < EXPERTS; ++e) {
      cursor[e] = off;
      int t = (cnt[e] + 127) >> 7;
      for (int i = 0; i < t; ++i) { tile_e[nt] = e; tile_r0[nt] = off + i * 128; ++nt; }
      off += t * 128;
    }
    *n_tiles = nt;
  }
}

__global__ void k_assign(const int* __restrict__ idx, const int* __restrict__ flag,
                         const float* __restrict__ wts, const float* __restrict__ scale,
                         int* cursor, int* slot_tok, int* tok_slot, float* slot_w) {
  int p = blockIdx.x * blockDim.x + threadIdx.x;
  if (p < NPAIR) {
    int e = expert_of(idx, *flag, p);
    int pos = atomicAdd(&cursor[e], 1);
    slot_tok[pos] = p >> 1;
    tok_slot[p] = pos;
    slot_w[pos] = wts[p] * scale[e];
  }
}

__global__ void k_cvt_x(const float* __restrict__ in, f16* __restrict__ out) {
  int i = blockIdx.x * blockDim.x + threadIdx.x;
  float4 v = ((const float4*)in)[i];
  f16x4 o = {(f16)v.x, (f16)v.y, (f16)v.z, (f16)v.w};
  ((f16x4*)out)[i] = o;
}

// ------------- 128x128x32 grouped GEMM, f32 weights consumed direct -------------
// 4 waves (2M x 2N), wave-out 64x64, acc[4][4]=64 VGPR, double-buffered LDS
// 32KB -> 3 blk/CU. Per kt:
//   A (f16, k-contig): gload_lds, linear dest, source-swizzled  [R4-proven]
//   B (f32 [k][n]): 8x coalesced float2 -> regs -> cvt f16 -> per-col
//     ds_write_b128 into B[col][k] layout with swz(col) XOR    [R4 read proven]
// 1 barrier/kt, counted vmcnt: issue order per kt = [gloadA x2][loadB x8];
// VMCNT(2)=B regs ready, VMCNT(8)=A landed (next B stays in flight).
// Dispatch: nt fastest (blockIdx.x), expert-major tiles (blockIdx.y) -> L3
// holds active expert slab (weights read from HBM ~once); xf/act L3-resident.
// G1: A = gathered xf; B = gate_up [2048][4096], tile cols = 64 gate + 64 up
//     (nt*64 strip); epilogue in-wave exact gelu(gate)*up -> act (64 cols).
// G0: A = act; B = down [2048][2048], 128-col strip -> y.
template <int G1>
__global__ __launch_bounds__(256, 3) void k_gemm(
    const f16* __restrict__ Asrc, const float* __restrict__ W,
    const int* __restrict__ slot_tok,
    const int* __restrict__ tile_e, const int* __restrict__ tile_r0,
    const int* __restrict__ n_tiles, f16* __restrict__ dst) {
  __shared__ __align__(16) f16 smem[2][8192];  // per buf: A 4096 f16, B 4096 f16

  const int bx = blockIdx.y;
  if (bx >= *n_tiles) return;
  const int nt = blockIdx.x;
  const int e = tile_e[bx];
  const int m0 = tile_r0[bx];
  const int LDB = G1 ? 4096 : 2048;

  const int tid = threadIdx.x;
  const int lane = tid & 63;
  const int wv = tid >> 6;
  const int wm = wv >> 1;   // 64-row band
  const int wn = wv & 1;    // col group
  const int fr = lane & 15;
  const int fhi = lane >> 4;

  // ---- A staging (gload_lds, linear dest, inverse-swizzled src) ----
  const f16* aS[2];
#pragma unroll
  for (int i = 0; i < 2; ++i) {
    const int r = i * 64 + (tid >> 2);            // tile row 0..127
    size_t arow = G1 ? (size_t)slot_tok[m0 + r] : (size_t)(m0 + r);
    aS[i] = Asrc + arow * 2048 + ((tid & 3) ^ swz(r)) * 8;
  }
  auto gloadA = [&](int s, int kt) {
#pragma unroll
    for (int i = 0; i < 2; ++i)
      gload_lds16(aS[i] + (size_t)kt * 32, &smem[s][i * 2048 + tid * 8]);
  };

  // ---- B staging: thread covers cols {2cp, 2cp+1} x k-octet kf ----
  const int cp = tid & 63;    // col pair 0..63 (tile cols 0..127)
  const int kf = tid >> 6;    // k-octet 0..3 (k = 8*kf .. 8*kf+7)
  int gcol;                   // global col of tile col 2cp
  if (G1) gcol = (cp < 32) ? nt * 64 + 2 * cp : 2048 + nt * 64 + (2 * cp - 64);
  else    gcol = nt * 128 + 2 * cp;
  const float* bP = W + (size_t)e * 2048 * LDB + (size_t)(8 * kf) * LDB + gcol;
  const int bbase = 2 * cp * 32 + ((kf ^ (cp & 3)) << 3);  // f16 units in B region

  float2 q0, q1, q2, q3, q4, q5, q6, q7;
  auto loadB = [&](int kt) {
    const float* p = bP + (size_t)kt * 32 * LDB;
    q0 = *(const float2*)(p);
    q1 = *(const float2*)(p + LDB);
    q2 = *(const float2*)(p + 2 * LDB);
    q3 = *(const float2*)(p + 3 * LDB);
    q4 = *(const float2*)(p + 4 * LDB);
    q5 = *(const float2*)(p + 5 * LDB);
    q6 = *(const float2*)(p + 6 * LDB);
    q7 = *(const float2*)(p + 7 * LDB);
  };
  auto writeB = [&](int s) {
    f16x8 wa = {(f16)q0.x, (f16)q1.x, (f16)q2.x, (f16)q3.x,
                (f16)q4.x, (f16)q5.x, (f16)q6.x, (f16)q7.x};
    f16x8 wb = {(f16)q0.y, (f16)q1.y, (f16)q2.y, (f16)q3.y,
                (f16)q4.y, (f16)q5.y, (f16)q6.y, (f16)q7.y};
    f16* B = &smem[s][4096];
    *(f16x8*)&B[bbase] = wa;        // col 2cp,  k-octet kf
    *(f16x8*)&B[bbase + 32] = wb;   // col 2cp+1 (same swizzle key: cp)
  };

  // B-frag col-tiles: G1 gate ct 0..3 (pairs with up ct 4..7 in-wave)
  int ctv[4];
#pragma unroll
  for (int ci = 0; ci < 4; ++ci) {
    if (G1) ctv[ci] = (ci < 2) ? (wn * 2 + ci) : (4 + wn * 2 + (ci - 2));
    else    ctv[ci] = wn * 4 + ci;
  }

  f32x4 acc[4][4];
#pragma unroll
  for (int i = 0; i < 4; ++i)
#pragma unroll
    for (int j = 0; j < 4; ++j) acc[i][j] = (f32x4){0.f, 0.f, 0.f, 0.f};

  // ---- prologue ----
  loadB(0);        // 8 vm (oldest)
  gloadA(0, 0);    // +2 vm
  VMCNT(2);        // B(0) regs ready (A(0) in flight)
  writeB(0);
  loadB(1);        // outstanding: A0(2) + B1(8)
  VMCNT(8);        // A(0) landed (B1 stays in flight)
  LGKM0();
  BARRIER();

  const int NT = 64;  // K/32
  for (int kt = 0; kt < NT; ++kt) {
    const int s = kt & 1;
    if (kt + 1 < NT) {
      gloadA(s ^ 1, kt + 1);   // 2 vm (newest)
      VMCNT(2);                // B(kt+1) regs ready (A's 2 remain)
      writeB(s ^ 1);
    }
    if (kt + 2 < NT) loadB(kt + 2);  // 8 vm; WAR on q after writeB

    // compute on buffer s (compiler schedules ds_read_b128 + waitcnts)
    const f16* As = &smem[s][0];
    const f16* Bs = &smem[s][4096];
    f16x8 af[4], bf[4];
#pragma unroll
    for (int mi = 0; mi < 4; ++mi) {
      const int r = wm * 64 + mi * 16 + fr;
      af[mi] = *(const f16x8*)&As[r * 32 + ((fhi ^ swz(r)) << 3)];
    }
#pragma unroll
    for (int ci = 0; ci < 4; ++ci) {
      const int c = ctv[ci] * 16 + fr;
      bf[ci] = *(const f16x8*)&Bs[c * 32 + ((fhi ^ swz(c)) << 3)];
    }
    __builtin_amdgcn_s_setprio(1);
#pragma unroll
    for (int mi = 0; mi < 4; ++mi)
#pragma unroll
      for (int ci = 0; ci < 4; ++ci)
        acc[mi][ci] = __builtin_amdgcn_mfma_f32_16x16x32_f16(af[mi], bf[ci],
                                                             acc[mi][ci], 0, 0, 0);
    __builtin_amdgcn_s_setprio(0);

    if (kt + 1 < NT) {
      if (kt + 2 < NT) { VMCNT(8); }  // A(kt+1) landed; B(kt+2) in flight
      else { VMCNT(0); }              // last prefetch round: drain all
      LGKM0();                        // writeB + frag reads drained
      BARRIER();
    }
  }

  // ---- epilogue (no LDS) ----
  if (G1) {
#pragma unroll
    for (int mi = 0; mi < 4; ++mi)
#pragma unroll
      for (int ci = 0; ci < 2; ++ci)
#pragma unroll
        for (int rg = 0; rg < 4; ++rg) {
          const int row = m0 + wm * 64 + mi * 16 + fhi * 4 + rg;
          const int col = nt * 64 + (wn * 2 + ci) * 16 + fr;
          const float g = acc[mi][ci][rg];
          const float u = acc[mi][ci + 2][rg];
          const float a = 0.5f * g * (1.0f + erff(g * 0.70710678118654752f)) * u;
          dst[(size_t)row * 2048 + col] = (f16)a;
        }
  } else {
#pragma unroll
    for (int mi = 0; mi < 4; ++mi)
#pragma unroll
      for (int ci = 0; ci < 4; ++ci)
#pragma unroll
        for (int rg = 0; rg < 4; ++rg) {
          const int row = m0 + wm * 64 + mi * 16 + fhi * 4 + rg;
          const int col = nt * 128 + wn * 64 + ci * 16 + fr;
          dst[(size_t)row * 2048 + col] = (f16)acc[mi][ci][rg];
        }
  }
}

// out[tok] = w(s0)*y[s0] + w(s1)*y[s1]  (fully writes out; no memset needed)
__global__ void k_combine(const f16* __restrict__ y, const float* __restrict__ slot_w,
                          const int* __restrict__ tok_slot, float* __restrict__ out) {
  const int gid = blockIdx.x * blockDim.x + threadIdx.x;
  const int tok = gid >> 8;
  const int c = (gid & 255) * 8;
  const int s0 = tok_slot[2 * tok], s1 = tok_slot[2 * tok + 1];
  const float w0 = slot_w[s0], w1 = slot_w[s1];
  const f16x8 v0 = *(const f16x8*)&y[(size_t)s0 * 2048 + c];
  const f16x8 v1 = *(const f16x8*)&y[(size_t)s1 * 2048 + c];
  float o[8];
#pragma unroll
  for (int j = 0; j < 8; ++j) o[j] = w0 * (float)v0[j] + w1 * (float)v1[j];
  float4* op = (float4*)&out[(size_t)tok * 2048 + c];
  op[0] = (float4){o[0], o[1], o[2], o[3]};
  op[1] = (float4){o[4], o[5], o[6], o[7]};
}

extern "C" void kernel_launch(void* const* d_in, const int* in_sizes, int n_in,
                              void* d_out, int out_size, void* d_ws, size_t ws_size,
                              hipStream_t stream) {
  const float* x = (const float*)d_in[0];
  const float* wts = (const float*)d_in[1];
  const int* idx = (const int*)d_in[2];
  const float* gup = (const float*)d_in[3];
  const float* dwn = (const float*)d_in[4];
  const float* scale = (const float*)d_in[5];
  float* out = (float*)d_out;

  char* ws = (char*)d_ws;
  f16* xf = (f16*)(ws + XF_OFF);
  f16* act = (f16*)(ws + ACT_OFF);
  f16* y = (f16*)(ws + Y_OFF);
  int* ctrl = (int*)(ws + CTRL_OFF);
  int* slot_tok = ctrl;
  int* tok_slot = ctrl + 9216;
  int* cnt = ctrl + 17408;
  int* cursor = ctrl + 17416;
  int* tile_e = ctrl + 17424;
  int* tile_r0 = ctrl + 17496;
  int* n_tiles = ctrl + 17568;
  int* is32 = ctrl + 17569;
  float* slot_w = (float*)(ctrl + 17576);

  hipMemsetAsync(ctrl, 0, (size_t)CTRL_INTS * sizeof(int), stream);

  k_detect<<<NPAIR / 2 / 256, 256, 0, stream>>>(idx, is32);
  k_count<<<NPAIR / 256, 256, 0, stream>>>(idx, is32, cnt);
  k_plan<<<1, 1, 0, stream>>>(cnt, cursor, tile_e, tile_r0, n_tiles);
  k_assign<<<NPAIR / 256, 256, 0, stream>>>(idx, is32, wts, scale, cursor,
                                            slot_tok, tok_slot, slot_w);
  k_cvt_x<<<NTOK * DDIM / 4 / 256, 256, 0, stream>>>(x, xf);
  k_gemm<1><<<dim3(32, MAXTILE), 256, 0, stream>>>(xf, gup, slot_tok, tile_e,
                                                   tile_r0, n_tiles, act);
  k_gemm<0><<<dim3(16, MAXTILE), 256, 0, stream>>>(act, dwn, slot_tok, tile_e,
                                                   tile_r0, n_tiles, y);
  k_combine<<<NTOK, 256, 0, stream>>>(y, slot_w, tok_slot, out);
}